// Round 1
// baseline (1043.180 us; speedup 1.0000x reference)
//
#include <hip/hip_runtime.h>

// ---------------- CSR build ----------------

__global__ void hist_k(const int* __restrict__ dst, int* __restrict__ counts, int E){
  int e = blockIdx.x*blockDim.x + threadIdx.x;
  if(e<E) atomicAdd(&counts[dst[e]], 1);
}

__global__ __launch_bounds__(1024) void scan1_k(const int* __restrict__ counts, int* __restrict__ excl,
                                                int* __restrict__ partials, int N){
  __shared__ int tmp[1024];
  int tid = threadIdx.x;
  int i = blockIdx.x*1024 + tid;
  int v = (i<N)? counts[i] : 0;
  tmp[tid] = v;
  __syncthreads();
  for(int off=1; off<1024; off<<=1){
    int t = (tid>=off)? tmp[tid-off] : 0;
    __syncthreads();
    tmp[tid] += t;
    __syncthreads();
  }
  if(i<N) excl[i] = tmp[tid] - v;
  if(tid==1023) partials[blockIdx.x] = tmp[tid];
}

__global__ void scan2_k(int* __restrict__ partials, int NB){
  __shared__ int tmp[64];
  int tid = threadIdx.x;
  int v = (tid<NB)? partials[tid] : 0;
  tmp[tid] = v;
  __syncthreads();
  for(int off=1; off<64; off<<=1){
    int t = (tid>=off)? tmp[tid-off] : 0;
    __syncthreads();
    tmp[tid] += t;
    __syncthreads();
  }
  if(tid<NB) partials[tid] = tmp[tid] - v;
}

__global__ __launch_bounds__(1024) void scan3_k(int* __restrict__ row_ptr, const int* __restrict__ partials,
                                                int* __restrict__ cursors, int N, int E){
  int i = blockIdx.x*1024 + threadIdx.x;
  if(i<N){
    int r = row_ptr[i] + partials[blockIdx.x];
    row_ptr[i] = r;
    cursors[i] = r;
  }
  if(i==0) row_ptr[N] = E;
}

__global__ void scatter_k(const int* __restrict__ src, const int* __restrict__ dst, int* __restrict__ cursors,
                          int* __restrict__ eperm, int* __restrict__ esrc, int E){
  int e = blockIdx.x*blockDim.x + threadIdx.x;
  if(e<E){
    int d = dst[e];
    int p = atomicAdd(&cursors[d], 1);
    eperm[p] = e;
    esrc[p] = src[e];
  }
}

// ---------------- per-layer kernels ----------------

// a_src[n] = aw[0:128].h[n]; a_dst[n] = aw[128:256].h[n] + ab. One wave/node.
__global__ void attn_k(const float* __restrict__ h, const float* __restrict__ aw, const float* __restrict__ ab,
                       float* __restrict__ a_src, float* __restrict__ a_dst, int N){
  int gid = blockIdx.x*blockDim.x + threadIdx.x;
  int n = gid >> 6, lane = gid & 63;
  if(n >= N) return;
  float2 hv = ((const float2*)(h + (size_t)n*128))[lane];
  float2 wa = ((const float2*)aw)[lane];
  float2 wb = ((const float2*)(aw+128))[lane];
  float s = hv.x*wa.x + hv.y*wa.y;
  float t = hv.x*wb.x + hv.y*wb.y;
  #pragma unroll
  for(int off=32; off>0; off>>=1){
    s += __shfl_xor(s, off, 64);
    t += __shfl_xor(t, off, 64);
  }
  if(lane==0){ a_src[n] = s; a_dst[n] = t + ab[0]; }
}

// One wave per dst node: segment softmax over incoming edges + weighted efeats sum.
// e >= 0 after relu, so max-init of 0 equals the reference's segment_max result.
__global__ void agg_k(const float* __restrict__ efeats, const float* __restrict__ a_src, const float* __restrict__ a_dst,
                      const int* __restrict__ row_ptr, const int* __restrict__ eperm, const int* __restrict__ esrc,
                      float* __restrict__ z, int N){
  int gid = blockIdx.x*blockDim.x + threadIdx.x;
  int n = gid >> 6, lane = gid & 63;
  if(n >= N) return;
  int beg = row_ptr[n], end = row_ptr[n+1];
  float2 acc; acc.x = 0.f; acc.y = 0.f;
  if(beg == end){ ((float2*)z)[(size_t)n*64 + lane] = acc; return; }
  float adn = a_dst[n];
  float m = 0.f;
  for(int i=beg;i<end;i++){
    float e = fmaxf(a_src[esrc[i]] + adn, 0.f);
    m = fmaxf(m, e);
  }
  float s = 0.f;
  for(int i=beg;i<end;i++){
    float e = fmaxf(a_src[esrc[i]] + adn, 0.f);
    s += __expf(e - m);
  }
  float inv = 1.f/s;
  for(int i=beg;i<end;i++){
    float e = fmaxf(a_src[esrc[i]] + adn, 0.f);
    float p = __expf(e - m);
    float2 fv = ((const float2*)(efeats + (size_t)eperm[i]*128))[lane];
    acc.x += p*fv.x; acc.y += p*fv.y;
  }
  acc.x *= inv; acc.y *= inv;
  ((float2*)z)[(size_t)n*64 + lane] = acc;
}

// out[n][o] = relu(bias[o] + sum_{k<128} W[o][k] h[n][k] + sum_{k<128} W[o][128+k] z[n][k])
// Register-tiled SGEMM: block tile 64 nodes x 128 outs, 256 threads, 4x8 micro-tile, KB=32.
__global__ __launch_bounds__(256) void update_k(const float* __restrict__ h, const float* __restrict__ z,
                                                const float* __restrict__ W, const float* __restrict__ bias,
                                                float* __restrict__ out, int N){
  __shared__ float xs[64][36];    // [node][k], pad keeps rows 16B-aligned
  __shared__ float ws[32][132];   // [k][o], pad keeps rows 16B-aligned
  int tid = threadIdx.x;
  int tx = tid & 15;   // out group: outs tx*8..tx*8+7
  int ty = tid >> 4;   // node group: nodes ty*4..ty*4+3
  int n0 = blockIdx.x * 64;
  float acc[4][8];
  #pragma unroll
  for(int i=0;i<4;i++)
    #pragma unroll
    for(int j=0;j<8;j++) acc[i][j] = 0.f;

  int lr = tid >> 2;          // x-stage: node row 0..63
  int lk = (tid & 3) * 8;     // x-stage: k offset
  int wo = tid >> 1;          // w-stage: out row 0..127
  int wk = (tid & 1) * 16;    // w-stage: k offset

  for(int kb=0; kb<256; kb+=32){
    {
      int node = n0 + lr;
      float4 v0 = make_float4(0.f,0.f,0.f,0.f), v1 = v0;
      if(node < N){
        int kg = kb + lk;
        const float* sp = (kg < 128) ? (h + (size_t)node*128 + kg)
                                     : (z + (size_t)node*128 + (kg-128));
        v0 = ((const float4*)sp)[0];
        v1 = ((const float4*)sp)[1];
      }
      *(float4*)&xs[lr][lk]   = v0;
      *(float4*)&xs[lr][lk+4] = v1;
    }
    {
      const float* wp = W + (size_t)wo*256 + kb + wk;
      float4 a0 = ((const float4*)wp)[0];
      float4 a1 = ((const float4*)wp)[1];
      float4 a2 = ((const float4*)wp)[2];
      float4 a3 = ((const float4*)wp)[3];
      float vals[16] = {a0.x,a0.y,a0.z,a0.w, a1.x,a1.y,a1.z,a1.w,
                        a2.x,a2.y,a2.z,a2.w, a3.x,a3.y,a3.z,a3.w};
      #pragma unroll
      for(int j=0;j<16;j++) ws[wk+j][wo] = vals[j];
    }
    __syncthreads();
    #pragma unroll 8
    for(int k=0;k<32;k++){
      float xv[4];
      #pragma unroll
      for(int i=0;i<4;i++) xv[i] = xs[ty*4+i][k];
      float4 w0 = *(const float4*)&ws[k][tx*8];
      float4 w1 = *(const float4*)&ws[k][tx*8+4];
      float wv[8] = {w0.x,w0.y,w0.z,w0.w, w1.x,w1.y,w1.z,w1.w};
      #pragma unroll
      for(int i=0;i<4;i++)
        #pragma unroll
        for(int j=0;j<8;j++)
          acc[i][j] += xv[i]*wv[j];
    }
    __syncthreads();
  }

  const float4* b4 = (const float4*)bias;
  float4 bb0 = b4[tx*2], bb1 = b4[tx*2+1];
  #pragma unroll
  for(int i=0;i<4;i++){
    int n = n0 + ty*4 + i;
    if(n >= N) continue;
    float4 r0, r1;
    r0.x = fmaxf(acc[i][0]+bb0.x, 0.f);
    r0.y = fmaxf(acc[i][1]+bb0.y, 0.f);
    r0.z = fmaxf(acc[i][2]+bb0.z, 0.f);
    r0.w = fmaxf(acc[i][3]+bb0.w, 0.f);
    r1.x = fmaxf(acc[i][4]+bb1.x, 0.f);
    r1.y = fmaxf(acc[i][5]+bb1.y, 0.f);
    r1.z = fmaxf(acc[i][6]+bb1.z, 0.f);
    r1.w = fmaxf(acc[i][7]+bb1.w, 0.f);
    float4* op = (float4*)(out + (size_t)n*128 + tx*8);
    op[0] = r0; op[1] = r1;
  }
}

// ---------------- driver ----------------

extern "C" void kernel_launch(void* const* d_in, const int* in_sizes, int n_in,
                              void* d_out, int out_size, void* d_ws, size_t ws_size,
                              hipStream_t stream){
  const float* nfeats = (const float*)d_in[0];
  const float* efeats = (const float*)d_in[1];
  const float* Ww0 = (const float*)d_in[2];
  const float* Wb0 = (const float*)d_in[3];
  const float* aw0 = (const float*)d_in[4];
  const float* ab0 = (const float*)d_in[5];
  const float* Ww1 = (const float*)d_in[6];
  const float* Wb1 = (const float*)d_in[7];
  const float* aw1 = (const float*)d_in[8];
  const float* ab1 = (const float*)d_in[9];
  const int* src = (const int*)d_in[10];
  const int* dst = (const int*)d_in[11];
  int E = in_sizes[10];
  int N = in_sizes[0] / 128;

  char* base = (char*)d_ws;
  size_t off = 0;
  auto take = [&](size_t bytes) -> char* {
    char* p = base + off;
    off = (off + bytes + 255) & ~(size_t)255;
    return p;
  };
  int*   counts  = (int*)take((size_t)N*4);
  int*   row_ptr = (int*)take((size_t)(N+1)*4);
  int*   cursors = (int*)take((size_t)N*4);
  int*   partials= (int*)take(256);
  int*   eperm   = (int*)take((size_t)E*4);
  int*   esrc    = (int*)take((size_t)E*4);
  float* a_src   = (float*)take((size_t)N*4);
  float* a_dst   = (float*)take((size_t)N*4);
  float* zbuf    = (float*)take((size_t)N*128*4);
  float* h1      = (float*)take((size_t)N*128*4);

  int NB = (N + 1023)/1024;   // 49 for N=50000 (must be <= 64 for scan2_k)

  hipMemsetAsync(counts, 0, (size_t)N*4, stream);
  hist_k<<<(E+255)/256, 256, 0, stream>>>(dst, counts, E);
  scan1_k<<<NB, 1024, 0, stream>>>(counts, row_ptr, partials, N);
  scan2_k<<<1, 64, 0, stream>>>(partials, NB);
  scan3_k<<<NB, 1024, 0, stream>>>(row_ptr, partials, cursors, N, E);
  scatter_k<<<(E+255)/256, 256, 0, stream>>>(src, dst, cursors, eperm, esrc, E);

  int agrid = (N + 3)/4;   // one wave per node, 4 waves per block
  // layer 1
  attn_k<<<agrid, 256, 0, stream>>>(nfeats, aw0, ab0, a_src, a_dst, N);
  agg_k<<<agrid, 256, 0, stream>>>(efeats, a_src, a_dst, row_ptr, eperm, esrc, zbuf, N);
  update_k<<<(N+63)/64, 256, 0, stream>>>(nfeats, zbuf, Ww0, Wb0, h1, N);
  // layer 2
  attn_k<<<agrid, 256, 0, stream>>>(h1, aw1, ab1, a_src, a_dst, N);
  agg_k<<<agrid, 256, 0, stream>>>(efeats, a_src, a_dst, row_ptr, eperm, esrc, zbuf, N);
  update_k<<<(N+63)/64, 256, 0, stream>>>(h1, zbuf, Ww1, Wb1, (float*)d_out, N);
}

// Round 2
// 761.034 us; speedup vs baseline: 1.3707x; 1.3707x over previous
//
#include <hip/hip_runtime.h>

// ---------------- CSR build ----------------

__global__ void hist_k(const int* __restrict__ dst, int* __restrict__ counts, int E){
  int e = blockIdx.x*blockDim.x + threadIdx.x;
  if(e<E) atomicAdd(&counts[dst[e]], 1);
}

__global__ __launch_bounds__(1024) void scan1_k(const int* __restrict__ counts, int* __restrict__ excl,
                                                int* __restrict__ partials, int N){
  __shared__ int tmp[1024];
  int tid = threadIdx.x;
  int i = blockIdx.x*1024 + tid;
  int v = (i<N)? counts[i] : 0;
  tmp[tid] = v;
  __syncthreads();
  for(int off=1; off<1024; off<<=1){
    int t = (tid>=off)? tmp[tid-off] : 0;
    __syncthreads();
    tmp[tid] += t;
    __syncthreads();
  }
  if(i<N) excl[i] = tmp[tid] - v;
  if(tid==1023) partials[blockIdx.x] = tmp[tid];
}

__global__ void scan2_k(int* __restrict__ partials, int NB){
  __shared__ int tmp[64];
  int tid = threadIdx.x;
  int v = (tid<NB)? partials[tid] : 0;
  tmp[tid] = v;
  __syncthreads();
  for(int off=1; off<64; off<<=1){
    int t = (tid>=off)? tmp[tid-off] : 0;
    __syncthreads();
    tmp[tid] += t;
    __syncthreads();
  }
  if(tid<NB) partials[tid] = tmp[tid] - v;
}

__global__ __launch_bounds__(1024) void scan3_k(int* __restrict__ row_ptr, const int* __restrict__ partials,
                                                int* __restrict__ cursors, int N, int E){
  int i = blockIdx.x*1024 + threadIdx.x;
  if(i<N){
    int r = row_ptr[i] + partials[blockIdx.x];
    row_ptr[i] = r;
    cursors[i] = r;
  }
  if(i==0) row_ptr[N] = E;
}

__global__ void scatter_k(const int* __restrict__ src, const int* __restrict__ dst, int* __restrict__ cursors,
                          int* __restrict__ eperm, int* __restrict__ esrc, int E){
  int e = blockIdx.x*blockDim.x + threadIdx.x;
  if(e<E){
    int d = dst[e];
    int p = atomicAdd(&cursors[d], 1);
    eperm[p] = e;
    esrc[p] = src[e];
  }
}

// ---------------- per-layer kernels ----------------

// a_src[n] = aw[0:128].h[n]; a_dst[n] = aw[128:256].h[n] + ab. One wave/node.
__global__ void attn_k(const float* __restrict__ h, const float* __restrict__ aw, const float* __restrict__ ab,
                       float* __restrict__ a_src, float* __restrict__ a_dst, int N){
  int gid = blockIdx.x*blockDim.x + threadIdx.x;
  int n = gid >> 6, lane = gid & 63;
  if(n >= N) return;
  float2 hv = ((const float2*)(h + (size_t)n*128))[lane];
  float2 wa = ((const float2*)aw)[lane];
  float2 wb = ((const float2*)(aw+128))[lane];
  float s = hv.x*wa.x + hv.y*wa.y;
  float t = hv.x*wb.x + hv.y*wb.y;
  #pragma unroll
  for(int off=32; off>0; off>>=1){
    s += __shfl_xor(s, off, 64);
    t += __shfl_xor(t, off, 64);
  }
  if(lane==0){ a_src[n] = s; a_dst[n] = t + ab[0]; }
}

// One wave per dst node. Single coalesced index load into registers (deg<=64 fast
// path), in-register shfl softmax, then 4-way-unrolled weighted row gather for MLP.
__global__ __launch_bounds__(256) void agg_k(const float* __restrict__ efeats,
    const float* __restrict__ a_src, const float* __restrict__ a_dst,
    const int* __restrict__ row_ptr, const int* __restrict__ eperm, const int* __restrict__ esrc,
    float* __restrict__ z, int N){
  int gid = blockIdx.x*blockDim.x + threadIdx.x;
  int n = gid >> 6, lane = gid & 63;
  if(n >= N) return;
  int beg = row_ptr[n], end = row_ptr[n+1];
  int deg = end - beg;
  float2 acc; acc.x = 0.f; acc.y = 0.f;
  if(deg <= 0){ ((float2*)z)[(size_t)n*64 + lane] = acc; return; }
  float adn = a_dst[n];

  // ---- phase A: logits for first chunk land in registers via one coalesced load
  int i = beg + lane;
  bool valid = i < end;
  int perm_reg = valid ? eperm[i] : 0;
  float e_reg = valid ? fmaxf(a_src[esrc[i]] + adn, 0.f) : -1e30f;

  float m = e_reg;
  #pragma unroll
  for(int off=32; off>0; off>>=1) m = fmaxf(m, __shfl_xor(m, off, 64));
  for(int c = beg + 64; c < end; c += 64){           // rare deg>64 path
    int ii = c + lane;
    float ev = (ii < end) ? fmaxf(a_src[esrc[ii]] + adn, 0.f) : -1e30f;
    #pragma unroll
    for(int off=32; off>0; off>>=1) ev = fmaxf(ev, __shfl_xor(ev, off, 64));
    m = fmaxf(m, ev);
  }

  float ex_reg = valid ? __expf(e_reg - m) : 0.f;
  float s = ex_reg;
  #pragma unroll
  for(int off=32; off>0; off>>=1) s += __shfl_xor(s, off, 64);
  for(int c = beg + 64; c < end; c += 64){           // rare deg>64 path
    int ii = c + lane;
    float ev = (ii < end) ? __expf(fmaxf(a_src[esrc[ii]] + adn, 0.f) - m) : 0.f;
    #pragma unroll
    for(int off=32; off>0; off>>=1) ev += __shfl_xor(ev, off, 64);
    s += ev;
  }
  float inv = 1.f / s;

  // ---- phase B: weighted gather; broadcast (p,row) from registers, 4 loads in flight
  const float2* ef2 = (const float2*)efeats;
  int cnt = min(deg, 64);
  int j = 0;
  for(; j + 4 <= cnt; j += 4){
    float p0 = __shfl(ex_reg, j+0, 64); int r0 = __shfl(perm_reg, j+0, 64);
    float p1 = __shfl(ex_reg, j+1, 64); int r1 = __shfl(perm_reg, j+1, 64);
    float p2 = __shfl(ex_reg, j+2, 64); int r2 = __shfl(perm_reg, j+2, 64);
    float p3 = __shfl(ex_reg, j+3, 64); int r3 = __shfl(perm_reg, j+3, 64);
    float2 f0 = ef2[(size_t)r0*64 + lane];
    float2 f1 = ef2[(size_t)r1*64 + lane];
    float2 f2 = ef2[(size_t)r2*64 + lane];
    float2 f3 = ef2[(size_t)r3*64 + lane];
    acc.x += p0*f0.x; acc.y += p0*f0.y;
    acc.x += p1*f1.x; acc.y += p1*f1.y;
    acc.x += p2*f2.x; acc.y += p2*f2.y;
    acc.x += p3*f3.x; acc.y += p3*f3.y;
  }
  for(; j < cnt; j++){
    float p = __shfl(ex_reg, j, 64); int r = __shfl(perm_reg, j, 64);
    float2 f = ef2[(size_t)r*64 + lane];
    acc.x += p*f.x; acc.y += p*f.y;
  }
  for(int c = beg + 64; c < end; c += 64){           // rare deg>64 path
    int ii = c + lane;
    bool v2 = ii < end;
    int pr = v2 ? eperm[ii] : 0;
    float er = v2 ? __expf(fmaxf(a_src[esrc[ii]] + adn, 0.f) - m) : 0.f;
    int cc = min(end - c, 64);
    for(int jj = 0; jj < cc; jj++){
      float p = __shfl(er, jj, 64); int r = __shfl(pr, jj, 64);
      float2 f = ef2[(size_t)r*64 + lane];
      acc.x += p*f.x; acc.y += p*f.y;
    }
  }

  acc.x *= inv; acc.y *= inv;
  ((float2*)z)[(size_t)n*64 + lane] = acc;
}

// out[n][o] = relu(bias[o] + sum_{k<128} W[o][k] h[n][k] + sum_{k<128} W[o][128+k] z[n][k])
// Register-tiled SGEMM: block tile 64 nodes x 128 outs, 256 threads, 4x8 micro-tile, KB=32.
__global__ __launch_bounds__(256) void update_k(const float* __restrict__ h, const float* __restrict__ z,
                                                const float* __restrict__ W, const float* __restrict__ bias,
                                                float* __restrict__ out, int N){
  __shared__ float xs[64][36];    // [node][k], pad keeps rows 16B-aligned
  __shared__ float ws[32][132];   // [k][o], pad keeps rows 16B-aligned
  int tid = threadIdx.x;
  int tx = tid & 15;   // out group: outs tx*8..tx*8+7
  int ty = tid >> 4;   // node group: nodes ty*4..ty*4+3
  int n0 = blockIdx.x * 64;
  float acc[4][8];
  #pragma unroll
  for(int i=0;i<4;i++)
    #pragma unroll
    for(int j=0;j<8;j++) acc[i][j] = 0.f;

  int lr = tid >> 2;          // x-stage: node row 0..63
  int lk = (tid & 3) * 8;     // x-stage: k offset
  int wo = tid >> 1;          // w-stage: out row 0..127
  int wk = (tid & 1) * 16;    // w-stage: k offset

  for(int kb=0; kb<256; kb+=32){
    {
      int node = n0 + lr;
      float4 v0 = make_float4(0.f,0.f,0.f,0.f), v1 = v0;
      if(node < N){
        int kg = kb + lk;
        const float* sp = (kg < 128) ? (h + (size_t)node*128 + kg)
                                     : (z + (size_t)node*128 + (kg-128));
        v0 = ((const float4*)sp)[0];
        v1 = ((const float4*)sp)[1];
      }
      *(float4*)&xs[lr][lk]   = v0;
      *(float4*)&xs[lr][lk+4] = v1;
    }
    {
      const float* wp = W + (size_t)wo*256 + kb + wk;
      float4 a0 = ((const float4*)wp)[0];
      float4 a1 = ((const float4*)wp)[1];
      float4 a2 = ((const float4*)wp)[2];
      float4 a3 = ((const float4*)wp)[3];
      float vals[16] = {a0.x,a0.y,a0.z,a0.w, a1.x,a1.y,a1.z,a1.w,
                        a2.x,a2.y,a2.z,a2.w, a3.x,a3.y,a3.z,a3.w};
      #pragma unroll
      for(int j=0;j<16;j++) ws[wk+j][wo] = vals[j];
    }
    __syncthreads();
    #pragma unroll 8
    for(int k=0;k<32;k++){
      float xv[4];
      #pragma unroll
      for(int i=0;i<4;i++) xv[i] = xs[ty*4+i][k];
      float4 w0 = *(const float4*)&ws[k][tx*8];
      float4 w1 = *(const float4*)&ws[k][tx*8+4];
      float wv[8] = {w0.x,w0.y,w0.z,w0.w, w1.x,w1.y,w1.z,w1.w};
      #pragma unroll
      for(int i=0;i<4;i++)
        #pragma unroll
        for(int j=0;j<8;j++)
          acc[i][j] += xv[i]*wv[j];
    }
    __syncthreads();
  }

  const float4* b4 = (const float4*)bias;
  float4 bb0 = b4[tx*2], bb1 = b4[tx*2+1];
  #pragma unroll
  for(int i=0;i<4;i++){
    int n = n0 + ty*4 + i;
    if(n >= N) continue;
    float4 r0, r1;
    r0.x = fmaxf(acc[i][0]+bb0.x, 0.f);
    r0.y = fmaxf(acc[i][1]+bb0.y, 0.f);
    r0.z = fmaxf(acc[i][2]+bb0.z, 0.f);
    r0.w = fmaxf(acc[i][3]+bb0.w, 0.f);
    r1.x = fmaxf(acc[i][4]+bb1.x, 0.f);
    r1.y = fmaxf(acc[i][5]+bb1.y, 0.f);
    r1.z = fmaxf(acc[i][6]+bb1.z, 0.f);
    r1.w = fmaxf(acc[i][7]+bb1.w, 0.f);
    float4* op = (float4*)(out + (size_t)n*128 + tx*8);
    op[0] = r0; op[1] = r1;
  }
}

// ---------------- driver ----------------

extern "C" void kernel_launch(void* const* d_in, const int* in_sizes, int n_in,
                              void* d_out, int out_size, void* d_ws, size_t ws_size,
                              hipStream_t stream){
  const float* nfeats = (const float*)d_in[0];
  const float* efeats = (const float*)d_in[1];
  const float* Ww0 = (const float*)d_in[2];
  const float* Wb0 = (const float*)d_in[3];
  const float* aw0 = (const float*)d_in[4];
  const float* ab0 = (const float*)d_in[5];
  const float* Ww1 = (const float*)d_in[6];
  const float* Wb1 = (const float*)d_in[7];
  const float* aw1 = (const float*)d_in[8];
  const float* ab1 = (const float*)d_in[9];
  const int* src = (const int*)d_in[10];
  const int* dst = (const int*)d_in[11];
  int E = in_sizes[10];
  int N = in_sizes[0] / 128;

  char* base = (char*)d_ws;
  size_t off = 0;
  auto take = [&](size_t bytes) -> char* {
    char* p = base + off;
    off = (off + bytes + 255) & ~(size_t)255;
    return p;
  };
  int*   counts  = (int*)take((size_t)N*4);
  int*   row_ptr = (int*)take((size_t)(N+1)*4);
  int*   cursors = (int*)take((size_t)N*4);
  int*   partials= (int*)take(256);
  int*   eperm   = (int*)take((size_t)E*4);
  int*   esrc    = (int*)take((size_t)E*4);
  float* a_src   = (float*)take((size_t)N*4);
  float* a_dst   = (float*)take((size_t)N*4);
  float* zbuf    = (float*)take((size_t)N*128*4);
  float* h1      = (float*)take((size_t)N*128*4);

  int NB = (N + 1023)/1024;   // 49 for N=50000 (must be <= 64 for scan2_k)

  hipMemsetAsync(counts, 0, (size_t)N*4, stream);
  hist_k<<<(E+255)/256, 256, 0, stream>>>(dst, counts, E);
  scan1_k<<<NB, 1024, 0, stream>>>(counts, row_ptr, partials, N);
  scan2_k<<<1, 64, 0, stream>>>(partials, NB);
  scan3_k<<<NB, 1024, 0, stream>>>(row_ptr, partials, cursors, N, E);
  scatter_k<<<(E+255)/256, 256, 0, stream>>>(src, dst, cursors, eperm, esrc, E);

  int agrid = (N + 3)/4;   // one wave per node, 4 waves per block
  // layer 1
  attn_k<<<agrid, 256, 0, stream>>>(nfeats, aw0, ab0, a_src, a_dst, N);
  agg_k<<<agrid, 256, 0, stream>>>(efeats, a_src, a_dst, row_ptr, eperm, esrc, zbuf, N);
  update_k<<<(N+63)/64, 256, 0, stream>>>(nfeats, zbuf, Ww0, Wb0, h1, N);
  // layer 2
  attn_k<<<agrid, 256, 0, stream>>>(h1, aw1, ab1, a_src, a_dst, N);
  agg_k<<<agrid, 256, 0, stream>>>(efeats, a_src, a_dst, row_ptr, eperm, esrc, zbuf, N);
  update_k<<<(N+63)/64, 256, 0, stream>>>(h1, zbuf, Ww1, Wb1, (float*)d_out, N);
}